// Round 5
// baseline (872.055 us; speedup 1.0000x reference)
//
#include <hip/hip_runtime.h>

#define B_DIM 256
#define H_DIM 4608
#define K_X   512
#define K_TOT 5120
#define NSPLIT 4
#define KSPL  (K_TOT / NSPLIT)   // 1280
#define NSTEP (KSPL / 32)        // 40
#define NTILE 288                // H_DIM / 16
#define TILE_FLOATS (256 * 64)   // dense per-tile chunk: 256 rows x 16 cols x 4 gates
#define G_SLICE ((long)NTILE * TILE_FLOATS)   // floats per split slice

typedef __attribute__((ext_vector_type(8))) short  short8;   // 8 x bf16
typedef __attribute__((ext_vector_type(4))) float  floatx4;  // MFMA C/D frag + NT vec

// Raw barrier: lgkmcnt(0) drains ds ops for cross-wave visibility, but no
// vmcnt(0) drain -> in-flight global prefetches survive the barrier.
#define BAR() do { \
  __builtin_amdgcn_sched_barrier(0); \
  asm volatile("s_waitcnt lgkmcnt(0)" ::: "memory"); \
  __builtin_amdgcn_s_barrier(); \
  __builtin_amdgcn_sched_barrier(0); \
} while (0)

static __device__ __forceinline__ unsigned pkbf(float a, float b){
  unsigned ua = (__float_as_uint(a) + 0x8000u) >> 16;
  unsigned ub = (__float_as_uint(b) + 0x8000u) & 0xFFFF0000u;
  return ua | ub;
}
static __device__ __forceinline__ float sigm(float v){ return 1.0f / (1.0f + __expf(-v)); }
static __device__ __forceinline__ float tanh_fast(float v){
  float ax = fabsf(v);
  float e  = __expf(-2.0f * ax);
  float t  = (1.0f - e) / (1.0f + e);
  return copysignf(t, v);
}

// ---------- kernel 0: pack [x|h0] -> bf16 A (256x5120); zero z ----------
__global__ __launch_bounds__(256) void conv_kernel(
    const float* __restrict__ x, const float* __restrict__ h0,
    unsigned short* __restrict__ Abf, float* __restrict__ z)
{
  const int t = threadIdx.x;
  if (blockIdx.x == 0) ((float4*)z)[t] = make_float4(0.f, 0.f, 0.f, 0.f); // 1024 floats

  const long e = ((long)blockIdx.x * 256 + t) * 8;     // element index, 8 per thread
  const int  b = (int)(e / K_TOT);
  const int  k = (int)(e - (long)b * K_TOT);
  const float* src = (k < K_X) ? (x + (long)b * K_X + k)
                               : (h0 + (long)b * H_DIM + (k - K_X));
  float4 v0 = *(const float4*)src;
  float4 v1 = *(const float4*)(src + 4);
  uint4 wv;
  wv.x = pkbf(v0.x, v0.y); wv.y = pkbf(v0.z, v0.w);
  wv.z = pkbf(v1.x, v1.y); wv.w = pkbf(v1.z, v1.w);
  *(uint4*)(Abf + e) = wv;
}

// ---------- kernel 1: split-K gates GEMM -> dense private partial tiles -----
// Grid: 288 j-tiles x 4 K-splits = 1152 blocks. Block: 4 waves, M=256 x N=64.
// Epilogue layout: G[split][tile][row][col16][gate4] -- each block owns one
// dense contiguous 64 KB chunk; float4 per (row,col) = (i,f,g,o). No false
// sharing across blocks/XCDs, full-line coalesced writes.
__global__ __launch_bounds__(256, 4) void lstm_gates_kernel(
    const unsigned short* __restrict__ Abf,
    const float* __restrict__ Wih, const float* __restrict__ Whh,
    float* __restrict__ G)
{
  __shared__ __align__(16) unsigned short Bs[2][64 * 32];  // 2 x 4 KB, swizzled

  const int t     = threadIdx.x;
  const int tile  = blockIdx.x >> 2;
  const int split = blockIdx.x & 3;
  const int kbase = split * KSPL;
  const int j0    = tile * 16;
  const int w     = t >> 6;
  const int l     = t & 63;
  const int q     = l >> 4;
  const int col   = l & 15;
  const int wrow  = w * 64;

  const long aBase = (long)(wrow + col) * K_TOT + kbase + q * 8;

  // B staging: thread covers W row rB, fp32 chunk cB (8 floats)
  const int  rB   = t >> 2;
  const int  cB   = t & 3;
  const int  gate = rB >> 4;
  const int  jl   = rB & 15;
  const long wrowg = (long)gate * H_DIM + j0 + jl;
  const float* __restrict__ pWx = Wih + wrowg * K_X   + cB * 8;
  const float* __restrict__ pWh = Whh + wrowg * H_DIM + cB * 8;

  // LDS cell for (row r, chunk c) at byte r*64 + ((c ^ ((r>>1)&3))<<4)
  char* ldsBase = (char*)&Bs[0][0];
  const int bwByte = rB  * 64 + ((cB ^ ((rB  >> 1) & 3)) << 4);   // write
  const int brByte = col * 64 + ((q  ^ ((col >> 1) & 3)) << 4);   // read (+nt*1024)

  floatx4 acc[4][4];
  #pragma unroll
  for (int mt = 0; mt < 4; ++mt)
    #pragma unroll
    for (int nt = 0; nt < 4; ++nt)
      acc[mt][nt] = (floatx4){0.f, 0.f, 0.f, 0.f};

  floatx4 pb[4][2];         // 4 rotating B prefetch slots (slot = tile & 3)
  short8 af0[4], af1[4];    // A-frag double buffer

  auto issueB = [&](int kt, int slot){
    const int ko = kbase + kt * 32;
    const float* p = (ko < K_X) ? (pWx + ko) : (pWh + (ko - K_X));
    pb[slot][0] = __builtin_nontemporal_load((const floatx4*)p);      // W is stream-once
    pb[slot][1] = __builtin_nontemporal_load((const floatx4*)p + 1);
  };
  auto writeB = [&](int slot, int buf){
    uint4 wv;
    wv.x = pkbf(pb[slot][0].x, pb[slot][0].y);
    wv.y = pkbf(pb[slot][0].z, pb[slot][0].w);
    wv.z = pkbf(pb[slot][1].x, pb[slot][1].y);
    wv.w = pkbf(pb[slot][1].z, pb[slot][1].w);
    *(uint4*)(ldsBase + buf * 4096 + bwByte) = wv;
  };
  auto loadA = [&](int kt, short8* af){
    const unsigned short* p = Abf + (aBase + kt * 32);
    #pragma unroll
    for (int mt = 0; mt < 4; ++mt)
      af[mt] = *(const short8*)(p + (long)mt * (16 * K_TOT));
  };
  auto mfmaStep = [&](int buf, const short8* af){
    short8 bf[4];
    #pragma unroll
    for (int nt = 0; nt < 4; ++nt)
      bf[nt] = *(const short8*)(ldsBase + buf * 4096 + brByte + nt * 1024);
    #pragma unroll
    for (int mt = 0; mt < 4; ++mt)
      #pragma unroll
      for (int nt = 0; nt < 4; ++nt)
        acc[mt][nt] = __builtin_amdgcn_mfma_f32_16x16x32_bf16(af[mt], bf[nt], acc[mt][nt], 0, 0, 0);
  };

  // prologue: tiles 0..3 in flight, tile 0 staged
  issueB(0, 0); issueB(1, 1); issueB(2, 2); issueB(3, 3);
  loadA(0, af0);
  writeB(0, 0);
  BAR();

  #pragma unroll 1
  for (int k = 0; k < NSTEP; k += 4){
    loadA(k + 1, af1);
    if (k + 4 < NSTEP) issueB(k + 4, 0);
    mfmaStep(0, af0);
    writeB(1, 1);
    BAR();
    loadA(k + 2, af0);
    if (k + 5 < NSTEP) issueB(k + 5, 1);
    mfmaStep(1, af1);
    writeB(2, 0);
    BAR();
    loadA(k + 3, af1);
    if (k + 6 < NSTEP) issueB(k + 6, 2);
    mfmaStep(0, af0);
    writeB(3, 1);
    BAR();
    if (k + 4 < NSTEP) loadA(k + 4, af0);
    if (k + 7 < NSTEP) issueB(k + 7, 3);
    mfmaStep(1, af1);
    if (k + 4 < NSTEP) writeB(0, 0);
    BAR();
  }

  // epilogue: dense float4 stores into this block's private contiguous chunk
  float* __restrict__ Gs = G + (long)split * G_SLICE + (long)tile * TILE_FLOATS;
  #pragma unroll
  for (int mt = 0; mt < 4; ++mt){
    #pragma unroll
    for (int r2 = 0; r2 < 4; ++r2){
      const int brow = wrow + mt * 16 + q * 4 + r2;
      floatx4 v = {acc[mt][0][r2], acc[mt][1][r2],
                   acc[mt][2][r2], acc[mt][3][r2]};
      __builtin_nontemporal_store(v, (floatx4*)(Gs + ((long)brow * 16 + col) * 4));
    }
  }
}

// ---------- kernel 2: sum split partials + bias + LSTM cell + z[b,r] --------
// G layout: [split][tile][row][col16][gate4]; float4 = (i,f,g,o) for one j.
__global__ __launch_bounds__(256) void cell_kernel(
    const float* __restrict__ G, const float* __restrict__ c0,
    const float* __restrict__ bih, const float* __restrict__ bhh,
    const float* __restrict__ x,
    float* __restrict__ outH, float* __restrict__ outC, float* __restrict__ z)
{
  const int b = blockIdx.x;
  const int t = threadIdx.x;
  const int l = t & 63;

  for (int jv = t; jv < H_DIM; jv += 256){
    const int tile = jv >> 4;
    const int jl   = jv & 15;
    const long gidx = (long)tile * TILE_FLOATS + (long)b * 64 + jl * 4;
    float4 s0 = *(const float4*)(G + gidx);
    float4 s1 = *(const float4*)(G + G_SLICE     + gidx);
    float4 s2 = *(const float4*)(G + G_SLICE * 2 + gidx);
    float4 s3 = *(const float4*)(G + G_SLICE * 3 + gidx);
    float gi = s0.x + s1.x + s2.x + s3.x + bih[jv]            + bhh[jv];
    float gf = s0.y + s1.y + s2.y + s3.y + bih[H_DIM + jv]    + bhh[H_DIM + jv];
    float gg = s0.z + s1.z + s2.z + s3.z + bih[2*H_DIM + jv]  + bhh[2*H_DIM + jv];
    float go = s0.w + s1.w + s2.w + s3.w + bih[3*H_DIM + jv]  + bhh[3*H_DIM + jv];
    float cp = c0[(long)b * H_DIM + jv];
    float cn = sigm(gf) * cp + sigm(gi) * tanh_fast(gg);
    float hn = sigm(go) * tanh_fast(cn);
    outC[(long)b * H_DIM + jv] = cn;
    outH[(long)b * H_DIM + jv] = hn;
    if (jv >= 2048 && jv < 4096){
      // wave spans 64 consecutive j -> single r region (512-wide, aligned)
      const int r = (jv - 2048) >> 9;
      float s = hn * x[(long)b * K_X + ((jv - 2048) & 511)];
      s += __shfl_xor(s, 32); s += __shfl_xor(s, 16); s += __shfl_xor(s, 8);
      s += __shfl_xor(s, 4);  s += __shfl_xor(s, 2);  s += __shfl_xor(s, 1);
      if (l == 0) atomicAdd(&z[b * 4 + r], s);
    }
  }
}

// ---------- kernel 3: y = x @ W0^T + dw1.z + db + b0  (MFMA, N-tile 16) ------
__global__ __launch_bounds__(256) void y_kernel(
    const unsigned short* __restrict__ Abf,
    const float* __restrict__ hnew,
    const float* __restrict__ W0, const float* __restrict__ b0,
    const float* __restrict__ z,
    float* __restrict__ y)
{
  __shared__ __align__(16) unsigned short Ws[16 * 512];  // 16 KB bf16 W0 tile, swizzled
  const int t    = threadIdx.x;
  const int w    = t >> 6;
  const int l    = t & 63;
  const int q    = l >> 4;
  const int col  = l & 15;
  const int n0   = blockIdx.x * 16;
  const int wrow = w * 64;

  {
    const int r  = t >> 4;
    const int kc = (t & 15) * 32;
    const float* src = W0 + (long)(n0 + r) * 512 + kc;
    #pragma unroll
    for (int j = 0; j < 4; ++j){
      float4 a = *(const float4*)(src + j * 8);
      float4 b = *(const float4*)(src + j * 8 + 4);
      uint4 wv;
      wv.x = pkbf(a.x, a.y); wv.y = pkbf(a.z, a.w);
      wv.z = pkbf(b.x, b.y); wv.w = pkbf(b.z, b.w);
      const int cch = (kc >> 3) + j;
      const int sw  = cch ^ (r & 7);
      *(uint4*)((char*)Ws + r * 1024 + sw * 16) = wv;
    }
  }
  __syncthreads();

  const long aBase = (long)(wrow + col) * K_TOT + q * 8;   // x lives in Abf cols 0..511
  floatx4 acc[4];
  #pragma unroll
  for (int mt = 0; mt < 4; ++mt) acc[mt] = (floatx4){0.f, 0.f, 0.f, 0.f};

  #pragma unroll 4
  for (int ks = 0; ks < 16; ++ks){
    const int sw = (ks * 4 + q) ^ (col & 7);
    short8 bf = *(const short8*)((char*)Ws + col * 1024 + sw * 16);
    #pragma unroll
    for (int mt = 0; mt < 4; ++mt){
      short8 af = *(const short8*)(Abf + aBase + ks * 32 + (long)mt * (16 * K_TOT));
      acc[mt] = __builtin_amdgcn_mfma_f32_16x16x32_bf16(af, bf, acc[mt], 0, 0, 0);
    }
  }

  const int   o  = n0 + col;
  const float bo = b0[o];
  #pragma unroll
  for (int mt = 0; mt < 4; ++mt){
    #pragma unroll
    for (int r2 = 0; r2 < 4; ++r2){
      const int brow = wrow + mt * 16 + q * 4 + r2;
      const float* hr = hnew + (long)brow * H_DIM;
      float4 d1 = *(const float4*)(hr + o * 4);        // dw1[b,o,0..3]
      float4 zr = *(const float4*)(z + brow * 4);      // z[b,0..3]
      float val = acc[mt][r2] + bo + hr[4096 + o]
                + d1.x * zr.x + d1.y * zr.y + d1.z * zr.z + d1.w * zr.w;
      y[(long)brow * 512 + o] = val;
    }
  }
}

extern "C" void kernel_launch(void* const* d_in, const int* in_sizes, int n_in,
                              void* d_out, int out_size, void* d_ws, size_t ws_size,
                              hipStream_t stream)
{
  (void)in_sizes; (void)n_in; (void)out_size; (void)ws_size;
  const float* x   = (const float*)d_in[0];
  const float* h0  = (const float*)d_in[1];
  const float* c0  = (const float*)d_in[2];
  const float* Wih = (const float*)d_in[3];
  const float* Whh = (const float*)d_in[4];
  const float* bih = (const float*)d_in[5];
  const float* bhh = (const float*)d_in[6];
  const float* W0  = (const float*)d_in[7];
  const float* b0  = (const float*)d_in[8];

  float* out  = (float*)d_out;
  float* y    = out;                       // 256*512
  float* outH = out + 131072;              // 256*4608
  float* outC = out + 131072 + 1179648;    // 256*4608

  unsigned short* Abf = (unsigned short*)d_ws;                          // 2.62 MB bf16 [x|h0]
  float* z = (float*)((char*)d_ws + (size_t)B_DIM * K_TOT * 2);         // 4 KB (256 x 4)
  float* G = (float*)((char*)d_ws + (size_t)B_DIM * K_TOT * 2 + 4096);  // 4 x 18.9 MB partials

  hipLaunchKernelGGL(conv_kernel, dim3(640), dim3(256), 0, stream, x, h0, Abf, z);
  hipLaunchKernelGGL(lstm_gates_kernel, dim3(NTILE * NSPLIT), dim3(256), 0, stream,
                     Abf, Wih, Whh, G);
  hipLaunchKernelGGL(cell_kernel, dim3(256), dim3(256), 0, stream,
                     G, c0, bih, bhh, x, outH, outC, z);
  hipLaunchKernelGGL(y_kernel, dim3(32), dim3(256), 0, stream, Abf, outH, W0, b0, z, y);
}